// Round 2
// baseline (890.199 us; speedup 1.0000x reference)
//
#include <hip/hip_runtime.h>
#include <hip/hip_bf16.h>

typedef __bf16 bf16;
typedef __bf16 bf16x8 __attribute__((ext_vector_type(8)));
typedef float  f32x4  __attribute__((ext_vector_type(4)));

#define TM 128
#define TN 128
#define TK 32
#define LDS_PAD 40   // bf16 elems per LDS row (32 data + 8 pad) — breaks pow2 bank strides

// Stage 8 elements (one 16B bf16 chunk) into LDS, converting fp32->bf16 if needed.
template<typename T>
__device__ inline void stage8(bf16* dst, const T* src) {
    if constexpr (sizeof(T) == 4) {           // fp32 source: 32B load -> 16B LDS
        const float4 f0 = *(const float4*)src;
        const float4 f1 = *(const float4*)(src + 4);
        bf16x8 v;
        v[0] = (bf16)f0.x; v[1] = (bf16)f0.y; v[2] = (bf16)f0.z; v[3] = (bf16)f0.w;
        v[4] = (bf16)f1.x; v[5] = (bf16)f1.y; v[6] = (bf16)f1.z; v[7] = (bf16)f1.w;
        *(bf16x8*)dst = v;
    } else {                                   // bf16 source: direct 16B copy
        *(uint4*)dst = *(const uint4*)src;
    }
}

// NT GEMM: C[m][n] = sum_k A[m][k] * B[n][k]  (+ bias)
// A: [M x K] (lda), B: [N x K] (ldb), C: [M x N] (ldc). TA/TB in {float,bf16},
// TC in {float,bf16}. BIAS: 0 none, 1 bias[n], 2 bias[m] (bias is fp32).
// blockIdx: x->n-tile, y->m-tile, z->batch (strides sA/sB/sC in elements).
template<typename TA, typename TB, typename TC, int BIAS>
__global__ __launch_bounds__(256)
void gemm_nt(const TA* __restrict__ A, const TB* __restrict__ B,
             TC* __restrict__ C, const float* __restrict__ bias,
             int K, int lda, int ldb, int ldc,
             long sA, long sB, long sC)
{
    __shared__ bf16 lsA[TM * LDS_PAD];
    __shared__ bf16 lsB[TN * LDS_PAD];

    const int bz = blockIdx.z;
    A += (long)bz * sA;
    B += (long)bz * sB;
    C += (long)bz * sC;

    const int m0 = blockIdx.y * TM;
    const int n0 = blockIdx.x * TN;

    const int t    = threadIdx.x;
    const int lane = t & 63;
    const int wave = t >> 6;
    const int wm   = (wave >> 1) * 64;  // wave's 64x64 quadrant of the 128x128 tile
    const int wn   = (wave & 1) * 64;
    const int lrow = lane & 15;
    const int quad = lane >> 4;

    // staging coords: each thread covers 8 contiguous k-elements of one row
    const int sr = t >> 2;        // 0..63
    const int sk = (t & 3) * 8;   // 0,8,16,24

    f32x4 acc[4][4] = {};

    for (int k0 = 0; k0 < K; k0 += TK) {
        __syncthreads();
        #pragma unroll
        for (int h = 0; h < 2; ++h) {
            const int row = h * 64 + sr;
            stage8(&lsA[row * LDS_PAD + sk], &A[(long)(m0 + row) * lda + k0 + sk]);
            stage8(&lsB[row * LDS_PAD + sk], &B[(long)(n0 + row) * ldb + k0 + sk]);
        }
        __syncthreads();

        bf16x8 af[4], bfr[4];
        #pragma unroll
        for (int i = 0; i < 4; ++i)
            af[i] = *(bf16x8*)&lsA[(wm + i * 16 + lrow) * LDS_PAD + quad * 8];
        #pragma unroll
        for (int j = 0; j < 4; ++j)
            bfr[j] = *(bf16x8*)&lsB[(wn + j * 16 + lrow) * LDS_PAD + quad * 8];

        #pragma unroll
        for (int i = 0; i < 4; ++i)
            #pragma unroll
            for (int j = 0; j < 4; ++j)
                acc[i][j] = __builtin_amdgcn_mfma_f32_16x16x32_bf16(
                    af[i], bfr[j], acc[i][j], 0, 0, 0);
    }

    // epilogue: C/D layout col = lane&15, row = quad*4 + reg
    #pragma unroll
    for (int i = 0; i < 4; ++i) {
        #pragma unroll
        for (int j = 0; j < 4; ++j) {
            #pragma unroll
            for (int r = 0; r < 4; ++r) {
                const int row = m0 + wm + i * 16 + quad * 4 + r;
                const int col = n0 + wn + j * 16 + lrow;
                float v = acc[i][j][r];
                if (BIAS == 1) v += bias[col];
                if (BIAS == 2) v += bias[row];
                C[(long)row * ldc + col] = (TC)v;
            }
        }
    }
}

// In-place masked softmax over fp32 rows of 2048. One block (256 thr) per row.
// score holds RAW (unscaled) q.k logits; applies mask (0 -> -inf), 1/32 scale,
// stable softmax; fully-masked rows -> 0.
__global__ __launch_bounds__(256)
void softmax_rows(float* __restrict__ score, const int* __restrict__ mask)
{
    const int t = threadIdx.x;
    const long base = (long)blockIdx.x * 2048 + t * 8;

    float4 a0 = *(const float4*)(score + base);
    float4 a1 = *(const float4*)(score + base + 4);
    int4 mA = *(const int4*)(mask + base);
    int4 mB = *(const int4*)(mask + base + 4);

    const float INV = 0.03125f;  // 1/sqrt(1024)
    float s[8];
    s[0] = mA.x ? a0.x * INV : -INFINITY;
    s[1] = mA.y ? a0.y * INV : -INFINITY;
    s[2] = mA.z ? a0.z * INV : -INFINITY;
    s[3] = mA.w ? a0.w * INV : -INFINITY;
    s[4] = mB.x ? a1.x * INV : -INFINITY;
    s[5] = mB.y ? a1.y * INV : -INFINITY;
    s[6] = mB.z ? a1.z * INV : -INFINITY;
    s[7] = mB.w ? a1.w * INV : -INFINITY;

    float mx = s[0];
    #pragma unroll
    for (int i = 1; i < 8; ++i) mx = fmaxf(mx, s[i]);
    #pragma unroll
    for (int o = 32; o > 0; o >>= 1) mx = fmaxf(mx, __shfl_xor(mx, o, 64));

    __shared__ float redm[4], reds[4];
    const int wave = t >> 6, lane = t & 63;
    if (lane == 0) redm[wave] = mx;
    __syncthreads();
    mx = fmaxf(fmaxf(redm[0], redm[1]), fmaxf(redm[2], redm[3]));

    const bool dead = !(mx > -INFINITY);   // fully-masked row
    float e[8], sum = 0.f;
    #pragma unroll
    for (int i = 0; i < 8; ++i) {
        const float x = dead ? 0.0f : __expf(s[i] - mx);
        e[i] = x;
        sum += x;
    }
    #pragma unroll
    for (int o = 32; o > 0; o >>= 1) sum += __shfl_xor(sum, o, 64);
    if (lane == 0) reds[wave] = sum;
    __syncthreads();
    sum = reds[0] + reds[1] + reds[2] + reds[3];

    const float inv = dead ? 0.0f : (1.0f / sum);
    float4 o0 = make_float4(e[0] * inv, e[1] * inv, e[2] * inv, e[3] * inv);
    float4 o1 = make_float4(e[4] * inv, e[5] * inv, e[6] * inv, e[7] * inv);
    *(float4*)(score + base)     = o0;
    *(float4*)(score + base + 4) = o1;
}

extern "C" void kernel_launch(void* const* d_in, const int* in_sizes, int n_in,
                              void* d_out, int out_size, void* d_ws, size_t ws_size,
                              hipStream_t stream)
{
    // setup_inputs order: key, query, mask, Wq, bq, Wk, bk, Wv, bv  (all fp32; mask int32)
    const float* key   = (const float*)d_in[0];   // [8,2048,1024]
    const float* query = (const float*)d_in[1];   // [8,2048,1024]
    const int*   mask  = (const int*)d_in[2];     // [8,2048,2048]
    const float* Wq = (const float*)d_in[3];      // [1024,1024]
    const float* bq = (const float*)d_in[4];
    const float* Wk = (const float*)d_in[5];
    const float* bk = (const float*)d_in[6];
    const float* Wv = (const float*)d_in[7];
    const float* bv = (const float*)d_in[8];

    float* out   = (float*)d_out;                        // [8,2048,1024]
    float* score = out + (size_t)8 * 2048 * 1024;        // [8,2048,2048]

    // workspace: q, k (bf16 [16384,1024]) + v-transposed (bf16 [8][1024][2048]) = 96 MB
    bf16* qb = (bf16*)d_ws;
    bf16* kb = qb + (size_t)16384 * 1024;
    bf16* vt = kb + (size_t)16384 * 1024;

    const dim3 blk(256, 1, 1);
    const long SB = (long)2048 * 1024;   // per-batch seq x hid stride
    const long SS = (long)2048 * 2048;   // per-batch seq x seq stride

    // q / k projections: [16384,1024] = X[16384,1024] . W[1024,1024]^T + b
    gemm_nt<float, float, bf16, 1><<<dim3(8, 128, 1), blk, 0, stream>>>(
        query, Wq, qb, bq, 1024, 1024, 1024, 1024, 0, 0, 0);
    gemm_nt<float, float, bf16, 1><<<dim3(8, 128, 1), blk, 0, stream>>>(
        key, Wk, kb, bk, 1024, 1024, 1024, 1024, 0, 0, 0);
    // v^T per batch: vt[b][h][s] = sum_e Wv[h][e] key[b][s][e] + bv[h]
    gemm_nt<float, float, bf16, 2><<<dim3(16, 8, 8), blk, 0, stream>>>(
        Wv, key, vt, bv, 1024, 1024, 1024, 2048, 0, SB, SB);
    // raw scores per batch: S[b][q][s] = sum_h qb[q][h] kb[s][h]  (fp32 out)
    gemm_nt<bf16, bf16, float, 0><<<dim3(16, 16, 8), blk, 0, stream>>>(
        qb, kb, score, nullptr, 1024, 1024, 1024, 2048, SB, SB, SS);
    // masked softmax in place (applies 1/32 scale and mask)
    softmax_rows<<<dim3(16384, 1, 1), blk, 0, stream>>>(score, mask);
    // output per batch: O[b][q][h] = sum_s P[b][q][s] vt[b][h][s]
    gemm_nt<float, bf16, float, 0><<<dim3(8, 16, 8), blk, 0, stream>>>(
        score, vt, out, nullptr, 2048, 2048, 2048, 1024, SS, SB, SB);
}

// Round 3
// 807.762 us; speedup vs baseline: 1.1021x; 1.1021x over previous
//
#include <hip/hip_runtime.h>
#include <hip/hip_bf16.h>

typedef __bf16 bf16;
typedef __bf16 bf16x8 __attribute__((ext_vector_type(8)));
typedef float  f32x4  __attribute__((ext_vector_type(4)));

#define TM 128
#define TN 128
#define TK 32
#define LDS_PAD 40   // fallback-path row stride

// ---- async global->LDS, 16B per lane; lds base must be wave-uniform ----
typedef __attribute__((address_space(3))) void       lds_t;
typedef __attribute__((address_space(1))) const void gbl_t;
__device__ __forceinline__ void async16(const void* g, void* l) {
    __builtin_amdgcn_global_load_lds((gbl_t*)g, (lds_t*)l, 16, 0, 0);
}

// ===================== fast path: bf16 NT GEMM with global_load_lds ========
// C[m][n] = sum_k A[m][k]*B[n][k] (+bias). A,B bf16. TC in {float,bf16}.
// BIAS: 0 none, 1 bias[n], 2 bias[m]. Unpadded LDS [128][TK]; per wave each
// async16 covers 16 consecutive rows x 64B (lane l -> row l>>2, chunk l&3).
template<typename TC, int BIAS>
__global__ __launch_bounds__(256)
void gemm_bt(const bf16* __restrict__ A, const bf16* __restrict__ B,
             TC* __restrict__ C, const float* __restrict__ bias,
             int K, int lda, int ldb, int ldc,
             long sA, long sB, long sC)
{
    __shared__ bf16 lsA[TM * TK];
    __shared__ bf16 lsB[TN * TK];

    const int bz = blockIdx.z;
    A += (long)bz * sA;  B += (long)bz * sB;  C += (long)bz * sC;

    const int m0 = blockIdx.y * TM;
    const int n0 = blockIdx.x * TN;

    const int t    = threadIdx.x;
    const int lane = t & 63;
    const int wave = t >> 6;
    const int wm   = (wave >> 1) * 64;   // wave's 64x64 quadrant
    const int wn   = (wave & 1) * 64;
    const int lrow = lane & 15;
    const int quad = lane >> 4;

    const int srow = lane >> 2;          // staging: row within 16-row group
    const int scol = (lane & 3) * 8;     // staging: elem offset (16B chunks)

    f32x4 acc[4][4] = {};

    for (int k0 = 0; k0 < K; k0 += TK) {
        __syncthreads();
        #pragma unroll
        for (int j = 0; j < 2; ++j) {
            const int rg = j * 64 + wave * 16;           // group base row
            async16(&A[(long)(m0 + rg + srow) * lda + k0 + scol], &lsA[rg * TK]);
            async16(&B[(long)(n0 + rg + srow) * ldb + k0 + scol], &lsB[rg * TK]);
        }
        __syncthreads();   // compiler inserts s_waitcnt vmcnt(0) before barrier

        bf16x8 af[4], bfr[4];
        #pragma unroll
        for (int i = 0; i < 4; ++i)
            af[i] = *(bf16x8*)&lsA[(wm + i * 16 + lrow) * TK + quad * 8];
        #pragma unroll
        for (int j = 0; j < 4; ++j)
            bfr[j] = *(bf16x8*)&lsB[(wn + j * 16 + lrow) * TK + quad * 8];

        #pragma unroll
        for (int i = 0; i < 4; ++i)
            #pragma unroll
            for (int j = 0; j < 4; ++j)
                acc[i][j] = __builtin_amdgcn_mfma_f32_16x16x32_bf16(
                    af[i], bfr[j], acc[i][j], 0, 0, 0);
    }

    // epilogue: C/D layout col = lane&15, row = quad*4 + reg
    #pragma unroll
    for (int i = 0; i < 4; ++i) {
        #pragma unroll
        for (int j = 0; j < 4; ++j) {
            #pragma unroll
            for (int r = 0; r < 4; ++r) {
                const int row = m0 + wm + i * 16 + quad * 4 + r;
                const int col = n0 + wn + j * 16 + lrow;
                float v = acc[i][j][r];
                if (BIAS == 1) v += bias[col];
                if (BIAS == 2) v += bias[row];
                C[(long)row * ldc + col] = (TC)v;
            }
        }
    }
}

// fp32 -> bf16 elementwise, 8 elems/thread; grid sized exactly (n % 2048 == 0)
__global__ __launch_bounds__(256)
void cvt_f32_bf16(const float* __restrict__ x, bf16* __restrict__ y)
{
    const long i = ((long)blockIdx.x * 256 + threadIdx.x) * 8;
    const float4 a = *(const float4*)(x + i);
    const float4 b = *(const float4*)(x + i + 4);
    bf16x8 v;
    v[0] = (bf16)a.x; v[1] = (bf16)a.y; v[2] = (bf16)a.z; v[3] = (bf16)a.w;
    v[4] = (bf16)b.x; v[5] = (bf16)b.y; v[6] = (bf16)b.z; v[7] = (bf16)b.w;
    *(bf16x8*)(y + i) = v;
}

// ===================== fallback path: fp32/bf16 manual staging GEMM ========
template<typename T>
__device__ inline void stage8(bf16* dst, const T* src) {
    if constexpr (sizeof(T) == 4) {
        const float4 f0 = *(const float4*)src;
        const float4 f1 = *(const float4*)(src + 4);
        bf16x8 v;
        v[0] = (bf16)f0.x; v[1] = (bf16)f0.y; v[2] = (bf16)f0.z; v[3] = (bf16)f0.w;
        v[4] = (bf16)f1.x; v[5] = (bf16)f1.y; v[6] = (bf16)f1.z; v[7] = (bf16)f1.w;
        *(bf16x8*)dst = v;
    } else {
        *(uint4*)dst = *(const uint4*)src;
    }
}

template<typename TA, typename TB, typename TC, int BIAS>
__global__ __launch_bounds__(256)
void gemm_nt(const TA* __restrict__ A, const TB* __restrict__ B,
             TC* __restrict__ C, const float* __restrict__ bias,
             int K, int lda, int ldb, int ldc,
             long sA, long sB, long sC)
{
    __shared__ bf16 lsA[TM * LDS_PAD];
    __shared__ bf16 lsB[TN * LDS_PAD];

    const int bz = blockIdx.z;
    A += (long)bz * sA;  B += (long)bz * sB;  C += (long)bz * sC;

    const int m0 = blockIdx.y * TM;
    const int n0 = blockIdx.x * TN;

    const int t    = threadIdx.x;
    const int lane = t & 63;
    const int wave = t >> 6;
    const int wm   = (wave >> 1) * 64;
    const int wn   = (wave & 1) * 64;
    const int lrow = lane & 15;
    const int quad = lane >> 4;
    const int sr = t >> 2;
    const int sk = (t & 3) * 8;

    f32x4 acc[4][4] = {};

    for (int k0 = 0; k0 < K; k0 += TK) {
        __syncthreads();
        #pragma unroll
        for (int h = 0; h < 2; ++h) {
            const int row = h * 64 + sr;
            stage8(&lsA[row * LDS_PAD + sk], &A[(long)(m0 + row) * lda + k0 + sk]);
            stage8(&lsB[row * LDS_PAD + sk], &B[(long)(n0 + row) * ldb + k0 + sk]);
        }
        __syncthreads();

        bf16x8 af[4], bfr[4];
        #pragma unroll
        for (int i = 0; i < 4; ++i)
            af[i] = *(bf16x8*)&lsA[(wm + i * 16 + lrow) * LDS_PAD + quad * 8];
        #pragma unroll
        for (int j = 0; j < 4; ++j)
            bfr[j] = *(bf16x8*)&lsB[(wn + j * 16 + lrow) * LDS_PAD + quad * 8];

        #pragma unroll
        for (int i = 0; i < 4; ++i)
            #pragma unroll
            for (int j = 0; j < 4; ++j)
                acc[i][j] = __builtin_amdgcn_mfma_f32_16x16x32_bf16(
                    af[i], bfr[j], acc[i][j], 0, 0, 0);
    }

    #pragma unroll
    for (int i = 0; i < 4; ++i) {
        #pragma unroll
        for (int j = 0; j < 4; ++j) {
            #pragma unroll
            for (int r = 0; r < 4; ++r) {
                const int row = m0 + wm + i * 16 + quad * 4 + r;
                const int col = n0 + wn + j * 16 + lrow;
                float v = acc[i][j][r];
                if (BIAS == 1) v += bias[col];
                if (BIAS == 2) v += bias[row];
                C[(long)row * ldc + col] = (TC)v;
            }
        }
    }
}

// ===================== softmax (optional bf16 dual write) ==================
template<int DUAL>
__global__ __launch_bounds__(256)
void softmax_rows(float* __restrict__ score, const int* __restrict__ mask,
                  bf16* __restrict__ pb)
{
    const int t = threadIdx.x;
    const long base = (long)blockIdx.x * 2048 + t * 8;

    float4 a0 = *(const float4*)(score + base);
    float4 a1 = *(const float4*)(score + base + 4);
    int4 mA = *(const int4*)(mask + base);
    int4 mB = *(const int4*)(mask + base + 4);

    const float INV = 0.03125f;  // 1/sqrt(1024)
    float s[8];
    s[0] = mA.x ? a0.x * INV : -INFINITY;
    s[1] = mA.y ? a0.y * INV : -INFINITY;
    s[2] = mA.z ? a0.z * INV : -INFINITY;
    s[3] = mA.w ? a0.w * INV : -INFINITY;
    s[4] = mB.x ? a1.x * INV : -INFINITY;
    s[5] = mB.y ? a1.y * INV : -INFINITY;
    s[6] = mB.z ? a1.z * INV : -INFINITY;
    s[7] = mB.w ? a1.w * INV : -INFINITY;

    float mx = s[0];
    #pragma unroll
    for (int i = 1; i < 8; ++i) mx = fmaxf(mx, s[i]);
    #pragma unroll
    for (int o = 32; o > 0; o >>= 1) mx = fmaxf(mx, __shfl_xor(mx, o, 64));

    __shared__ float redm[4], reds[4];
    const int wave = t >> 6, lane = t & 63;
    if (lane == 0) redm[wave] = mx;
    __syncthreads();
    mx = fmaxf(fmaxf(redm[0], redm[1]), fmaxf(redm[2], redm[3]));

    const bool dead = !(mx > -INFINITY);
    float e[8], sum = 0.f;
    #pragma unroll
    for (int i = 0; i < 8; ++i) {
        const float x = dead ? 0.0f : __expf(s[i] - mx);
        e[i] = x;
        sum += x;
    }
    #pragma unroll
    for (int o = 32; o > 0; o >>= 1) sum += __shfl_xor(sum, o, 64);
    if (lane == 0) reds[wave] = sum;
    __syncthreads();
    sum = reds[0] + reds[1] + reds[2] + reds[3];

    const float inv = dead ? 0.0f : (1.0f / sum);
    float p[8];
    #pragma unroll
    for (int i = 0; i < 8; ++i) p[i] = e[i] * inv;

    *(float4*)(score + base)     = make_float4(p[0], p[1], p[2], p[3]);
    *(float4*)(score + base + 4) = make_float4(p[4], p[5], p[6], p[7]);
    if (DUAL) {
        bf16x8 v;
        #pragma unroll
        for (int i = 0; i < 8; ++i) v[i] = (bf16)p[i];
        *(bf16x8*)(pb + base) = v;
    }
}

extern "C" void kernel_launch(void* const* d_in, const int* in_sizes, int n_in,
                              void* d_out, int out_size, void* d_ws, size_t ws_size,
                              hipStream_t stream)
{
    const float* key   = (const float*)d_in[0];   // [8,2048,1024]
    const float* query = (const float*)d_in[1];   // [8,2048,1024]
    const int*   mask  = (const int*)d_in[2];     // [8,2048,2048]
    const float* Wq = (const float*)d_in[3];
    const float* bq = (const float*)d_in[4];
    const float* Wk = (const float*)d_in[5];
    const float* bk = (const float*)d_in[6];
    const float* Wv = (const float*)d_in[7];
    const float* bv = (const float*)d_in[8];

    float* out   = (float*)d_out;                      // [8,2048,1024]
    float* score = out + (size_t)8 * 2048 * 1024;      // [8,2048,2048]

    const dim3 blk(256, 1, 1);
    const long SB = (long)2048 * 1024;
    const long SS = (long)2048 * 2048;
    const size_t NX = (size_t)8 * 2048 * 1024;         // 16.8M elems
    const size_t NW = (size_t)1024 * 1024;

    // fast-path ws layout (bf16 elems): xb | qb | kb | vt | wq | wk | wv
    // Pb (32M elems) aliases [xb qb] (both dead by softmax time).
    const size_t NEED = (4 * NX + 3 * NW) * sizeof(bf16);

    if (ws_size >= NEED) {
        bf16* xb = (bf16*)d_ws;
        bf16* qb = xb + NX;
        bf16* kb = qb + NX;
        bf16* vt = kb + NX;
        bf16* wq = vt + NX;
        bf16* wk = wq + NW;
        bf16* wv = wk + NW;
        bf16* Pb = xb;                                  // alias over xb+qb

        cvt_f32_bf16<<<dim3(NW / 2048), blk, 0, stream>>>(Wq, wq);
        cvt_f32_bf16<<<dim3(NW / 2048), blk, 0, stream>>>(Wk, wk);
        cvt_f32_bf16<<<dim3(NW / 2048), blk, 0, stream>>>(Wv, wv);

        // key -> xb; then k-projection and v^T (both consume xb)
        cvt_f32_bf16<<<dim3(NX / 2048), blk, 0, stream>>>(key, xb);
        gemm_bt<bf16, 1><<<dim3(8, 128, 1), blk, 0, stream>>>(
            xb, wk, kb, bk, 1024, 1024, 1024, 1024, 0, 0, 0);
        gemm_bt<bf16, 2><<<dim3(16, 8, 8), blk, 0, stream>>>(
            wv, xb, vt, bv, 1024, 1024, 1024, 2048, 0, SB, SB);

        // query -> xb (reuse); q-projection
        cvt_f32_bf16<<<dim3(NX / 2048), blk, 0, stream>>>(query, xb);
        gemm_bt<bf16, 1><<<dim3(8, 128, 1), blk, 0, stream>>>(
            xb, wq, qb, bq, 1024, 1024, 1024, 1024, 0, 0, 0);

        // raw scores (fp32) -> d_out score region
        gemm_bt<float, 0><<<dim3(16, 16, 8), blk, 0, stream>>>(
            qb, kb, score, nullptr, 1024, 1024, 1024, 2048, SB, SB, SS);

        // masked softmax: fp32 in place + bf16 copy to Pb
        softmax_rows<1><<<dim3(16384), blk, 0, stream>>>(score, mask, Pb);

        // O = P . vt
        gemm_bt<float, 0><<<dim3(8, 16, 8), blk, 0, stream>>>(
            Pb, vt, out, nullptr, 2048, 2048, 2048, 1024, SS, SB, SB);
    } else {
        // fallback: round-2 passing path (fp32 staging, 100.7 MB ws)
        bf16* qb = (bf16*)d_ws;
        bf16* kb = qb + NX;
        bf16* vt = kb + NX;

        gemm_nt<float, float, bf16, 1><<<dim3(8, 128, 1), blk, 0, stream>>>(
            query, Wq, qb, bq, 1024, 1024, 1024, 1024, 0, 0, 0);
        gemm_nt<float, float, bf16, 1><<<dim3(8, 128, 1), blk, 0, stream>>>(
            key, Wk, kb, bk, 1024, 1024, 1024, 1024, 0, 0, 0);
        gemm_nt<float, float, bf16, 2><<<dim3(16, 8, 8), blk, 0, stream>>>(
            Wv, key, vt, bv, 1024, 1024, 1024, 2048, 0, SB, SB);
        gemm_nt<bf16, bf16, float, 0><<<dim3(16, 16, 8), blk, 0, stream>>>(
            qb, kb, score, nullptr, 1024, 1024, 1024, 2048, SB, SB, SS);
        softmax_rows<0><<<dim3(16384), blk, 0, stream>>>(score, mask, nullptr);
        gemm_nt<float, bf16, float, 0><<<dim3(8, 16, 8), blk, 0, stream>>>(
            score, vt, out, nullptr, 2048, 2048, 2048, 1024, SS, SB, SB);
    }
}